// Round 8
// baseline (1270.778 us; speedup 1.0000x reference)
//
#include <hip/hip_runtime.h>
#include <hip/hip_bf16.h>
#include <cstdint>

// B=16384, L=5, D=1024.  M = 81920 rows.
// scores = x^T (Wq^T Wk) x  ->  Gt[n,k]; u = x@Gt^T; s = rowdot(u,x)/32.
// Pipeline:
//   k_cvt_bf16: x->xb ; Wv->Bcat[1024:2048] ; W1->W1b ; W2->W2b
//   k_gt:       Gt -> Bcat[0:1024]
//   k_gemm256<0>: xb @ Bcat^T; u-tiles (n0<1024) -> fused rowdot(u,x) partials
//                 into scp[16][M] (slot = n-tile*4 + wn; never materialize u);
//                 v-tiles -> vb bf16 [M][1024]
//   k_attn_ln:  sc=sum16(scp)/32 ->softmax->attn, y = LN(attn+x) -> xb in place
//   k_gemm256<1>: h = GELU(y @ W1^T + b1) -> hb
//   k_gemm256<3>: z = h @ W2^T + b2 + y -> zb bf16 (ws)
//   k_ln_final_bf: LN(z)*ff_g+ff_b -> d_out fp32
//
// GEMM: 256x256 tile, BK=32, ring-3 LDS buffers (96 KiB), ONE barrier per
// K-step: per step {12 ds_read frags; stage step s+2 (4 gload_lds);
// setprio(1); 32 MFMA; setprio(0); vmcnt(4); s_barrier}.  Waves free-run
// within a step (no lgkmcnt(0) lockstep) -> cross-wave ds_read||MFMA overlap.
// R7 bug fixed here: rowdot partials are per-(n-tile,wn) slots — previously
// the 4 wn-waves clobbered one slot (3/4 of score lost, absmax 1.05).

typedef float f32x4 __attribute__((ext_vector_type(4)));
typedef __bf16 bf16x8 __attribute__((ext_vector_type(8)));

#define DD 1024
#define NROWS 81920L

__device__ __forceinline__ unsigned short f2bf(float f) {
  union { float f; unsigned u; } c; c.f = f;
  unsigned u = c.u;
  return (unsigned short)((u + 0x7FFFu + ((u >> 16) & 1u)) >> 16);  // RNE
}
__device__ __forceinline__ float bf2f(unsigned short b) {
  union { unsigned u; float f; } c; c.u = ((unsigned)b) << 16;
  return c.f;
}
__device__ __forceinline__ void unpack8(uint4 v, float* o) {
  o[0] = bf2f((unsigned short)(v.x & 0xffffu)); o[1] = bf2f((unsigned short)(v.x >> 16));
  o[2] = bf2f((unsigned short)(v.y & 0xffffu)); o[3] = bf2f((unsigned short)(v.y >> 16));
  o[4] = bf2f((unsigned short)(v.z & 0xffffu)); o[5] = bf2f((unsigned short)(v.z >> 16));
  o[6] = bf2f((unsigned short)(v.w & 0xffffu)); o[7] = bf2f((unsigned short)(v.w >> 16));
}
__device__ __forceinline__ void gload_lds16(const void* g, void* l) {
  __builtin_amdgcn_global_load_lds(
      (const __attribute__((address_space(1))) unsigned int*)g,
      (__attribute__((address_space(3))) unsigned int*)l, 16, 0, 0);
}

// ---------------- fp32 -> bf16 ----------------
__global__ void __launch_bounds__(256) k_cvt_bf16(const float* __restrict__ in,
                                                  unsigned short* __restrict__ out, long n) {
  long i = ((long)blockIdx.x * blockDim.x + threadIdx.x) * 8;
  long stride = (long)gridDim.x * blockDim.x * 8;
  for (; i < n; i += stride) {
    f32x4 a = *(const f32x4*)(in + i);
    f32x4 b = *(const f32x4*)(in + i + 4);
    uint4 o;
    o.x = (unsigned)f2bf(a[0]) | ((unsigned)f2bf(a[1]) << 16);
    o.y = (unsigned)f2bf(a[2]) | ((unsigned)f2bf(a[3]) << 16);
    o.z = (unsigned)f2bf(b[0]) | ((unsigned)f2bf(b[1]) << 16);
    o.w = (unsigned)f2bf(b[2]) | ((unsigned)f2bf(b[3]) << 16);
    *(uint4*)(out + i) = o;
  }
}

// ---------------- Gt[n,k] = sum_e Wk[e,n] * Wq[e,k] ----------------
__global__ void __launch_bounds__(256) k_gt(const float* __restrict__ Wq,
                                            const float* __restrict__ Wk,
                                            unsigned short* __restrict__ Gt) {
  __shared__ float sk[16][16];
  __shared__ float sq[16][64];
  const int tx = threadIdx.x, ty = threadIdx.y;
  const int n0 = blockIdx.y * 16;
  const int k0 = blockIdx.x * 64;
  float acc[4] = {0.f, 0.f, 0.f, 0.f};
  for (int e0 = 0; e0 < 1024; e0 += 16) {
    sk[ty][tx] = Wk[(long)(e0 + ty) * DD + n0 + tx];
    *(f32x4*)&sq[ty][tx * 4] = *(const f32x4*)&Wq[(long)(e0 + ty) * DD + k0 + tx * 4];
    __syncthreads();
#pragma unroll
    for (int ee = 0; ee < 16; ++ee) {
      float kv = sk[ee][ty];
      f32x4 qv = *(const f32x4*)&sq[ee][tx * 4];
      acc[0] += kv * qv[0]; acc[1] += kv * qv[1];
      acc[2] += kv * qv[2]; acc[3] += kv * qv[3];
    }
    __syncthreads();
  }
  uint2 o;
  o.x = (unsigned)f2bf(acc[0]) | ((unsigned)f2bf(acc[1]) << 16);
  o.y = (unsigned)f2bf(acc[2]) | ((unsigned)f2bf(acc[3]) << 16);
  *(uint2*)&Gt[(long)(n0 + ty) * DD + k0 + tx * 4] = o;
}

// ---------------- 256x256 BT-GEMM, BK=32, ring-3, barrier-light ----------------
// EPI 0: u-tiles -> rowdot partials to scp[16][M]; v-tiles -> bf16 vb.
// EPI 1: GELU(acc+bias) bf16.  EPI 2: acc+bias+resid -> fp32.
// EPI 3: acc+bias+resid -> bf16.

// TAILV: 1 = vmcnt(4)+barrier, 2 = vmcnt(0)+barrier, 3 = none (last step)
#define STEP(RBUF, SBUF, S, DOSTAGE, TAILV)                                    \
  {                                                                            \
    const char* bA_ = ldsB + (RBUF) * 32768;                                   \
    const char* bB_ = bA_ + 16384;                                             \
    bf16x8 fa[8], fb[4];                                                       \
    _Pragma("unroll") for (int i = 0; i < 8; ++i)                              \
      fa[i] = *(const bf16x8*)(bA_ + aoff[i]);                                 \
    _Pragma("unroll") for (int j = 0; j < 4; ++j)                              \
      fb[j] = *(const bf16x8*)(bB_ + boff[j]);                                 \
    if (DOSTAGE) stage((S) + 2, ldsB + (SBUF) * 32768);                        \
    __builtin_amdgcn_s_setprio(1);                                             \
    _Pragma("unroll") for (int i = 0; i < 8; ++i)                              \
      _Pragma("unroll") for (int j = 0; j < 4; ++j)                            \
        acc[i][j] = __builtin_amdgcn_mfma_f32_16x16x32_bf16(                   \
            fa[i], fb[j], acc[i][j], 0, 0, 0);                                 \
    __builtin_amdgcn_s_setprio(0);                                             \
    if ((TAILV) == 1) asm volatile("s_waitcnt vmcnt(4)" ::: "memory");         \
    else if ((TAILV) == 2) asm volatile("s_waitcnt vmcnt(0)" ::: "memory");    \
    if ((TAILV) != 3) {                                                        \
      __builtin_amdgcn_s_barrier();                                            \
      asm volatile("" ::: "memory");                                           \
    }                                                                          \
  }

template <int EPI>
__global__ void __launch_bounds__(512, 2) k_gemm256(
    const unsigned short* __restrict__ A,   // [M,1024] bf16
    const unsigned short* __restrict__ B,   // [N,1024] bf16 (BT layout)
    unsigned short* __restrict__ outb,
    float* __restrict__ outf,
    const float* __restrict__ bias,
    const unsigned short* __restrict__ resid,
    float* __restrict__ scp,                 // [16][M] rowdot partials (EPI 0)
    const int ntl2,                          // log2(n-tiles)
    const int cst) {                         // C col-stride (elems)
  // ring-3: buffer p at p*32768; A [256 rows][64B] at 0, B at +16384
  __shared__ __align__(16) char ldsB[98304];
  const int tid = threadIdx.x;
  const int lane = tid & 63;
  const int wid = tid >> 6;
  const int wm = wid >> 2, wn = wid & 3;

  // bijective XCD chunking; m-major so n-blocks sharing an A-strip co-reside
  const int nwg = gridDim.x;
  const int cpx = nwg >> 3;
  const int dd = blockIdx.x;
  const int lgc = (dd & 7) * cpx + (dd >> 3);
  const int mt = lgc >> ntl2;
  const int nt = lgc & ((1 << ntl2) - 1);
  const long m0 = (long)mt * 256;
  const int n0 = nt * 256;

  // ---- staging: per step 16 KB A + 16 KB B = 2+2 gload_lds per thread ----
  // LDS dest linear (tid*16, +8192); global source granule pre-swizzled:
  // (tid&3) ^ ((row>>1)&3), row = tid>>2 (bits 1-2 invariant under +128).
  const int q = tid >> 2;
  const int gcol = (((tid & 3) ^ ((q >> 1) & 3)) << 4);
  const char* gA = (const char*)A + (m0 + q) * 2048 + gcol;
  const char* gB = (const char*)B + ((long)n0 + q) * 2048 + gcol;
  const int ldst = tid * 16;

  auto stage = [&](int s, char* base) {
    const char* sa = gA + (long)s * 64;
    const char* sb = gB + (long)s * 64;
    gload_lds16(sa, base + ldst);
    gload_lds16(sa + 128 * 2048, base + 8192 + ldst);
    gload_lds16(sb, base + 16384 + ldst);
    gload_lds16(sb + 128 * 2048, base + 24576 + ldst);
  };

  // ---- fragment read offsets (swizzled to match) ----
  const int la = lane & 15, lg = lane >> 4;
  const int cb = ((lg ^ ((la >> 1) & 3)) << 4);
  int aoff[8], boff[4];
#pragma unroll
  for (int mi = 0; mi < 8; ++mi) aoff[mi] = (wm * 128 + mi * 16 + la) * 64 + cb;
#pragma unroll
  for (int nj = 0; nj < 4; ++nj) boff[nj] = (wn * 64 + nj * 16 + la) * 64 + cb;

  f32x4 acc[8][4];
#pragma unroll
  for (int mi = 0; mi < 8; ++mi)
#pragma unroll
    for (int nj = 0; nj < 4; ++nj) acc[mi][nj] = f32x4{0.f, 0.f, 0.f, 0.f};

  // ---- prologue: stage steps 0,1; wait step 0 (4 oldest); barrier ----
  stage(0, ldsB);
  stage(1, ldsB + 32768);
  asm volatile("s_waitcnt vmcnt(4)" ::: "memory");
  __builtin_amdgcn_s_barrier();
  asm volatile("" ::: "memory");

  // ---- main: 32 K-steps, ring-3, stage s+2 during s ----
  for (int st = 0; st < 30; st += 3) {
    STEP(0, 2, st + 0, true, 1);
    STEP(1, 0, st + 1, true, 1);
    STEP(2, 1, st + 2, true, 1);
  }
  STEP(0, 2, 30, false, 2);
  STEP(1, 0, 31, false, 3);

  // ---- epilogue ----
  const long rbase = m0 + wm * 128 + (lane >> 4) * 4;
  const int cbase = n0 + wn * 64 + la;
  if constexpr (EPI == 0) {
    if (n0 < 1024) {
      // fused rowdot(u, x): x == A tile of this block (L2-hot).
      // Slot per (n-tile, wn): the 4 wn-waves cover disjoint 64-col slices.
      float* sp = scp + ((long)(n0 >> 8) * 4 + wn) * NROWS;
#pragma unroll
      for (int mi = 0; mi < 8; ++mi) {
#pragma unroll
        for (int t = 0; t < 4; ++t) {
          const long r = rbase + mi * 16 + t;
          float s = 0.f;
#pragma unroll
          for (int nj = 0; nj < 4; ++nj)
            s += acc[mi][nj][t] * bf2f(A[r * DD + cbase + nj * 16]);
          s += __shfl_xor(s, 1);
          s += __shfl_xor(s, 2);
          s += __shfl_xor(s, 4);
          s += __shfl_xor(s, 8);
          if (la == 0) sp[r] = s;
        }
      }
    } else {
#pragma unroll
      for (int mi = 0; mi < 8; ++mi)
#pragma unroll
        for (int nj = 0; nj < 4; ++nj) {
          const int col = cbase + nj * 16 - 1024;
#pragma unroll
          for (int t = 0; t < 4; ++t) {
            const long r = rbase + mi * 16 + t;
            outb[r * 1024 + col] = f2bf(acc[mi][nj][t]);
          }
        }
    }
  } else {
#pragma unroll
    for (int mi = 0; mi < 8; ++mi) {
#pragma unroll
      for (int nj = 0; nj < 4; ++nj) {
        const int col = cbase + nj * 16;
        const float bv = bias[col];
#pragma unroll
        for (int t = 0; t < 4; ++t) {
          const long r = rbase + mi * 16 + t;
          float v = acc[mi][nj][t];
          if constexpr (EPI == 1) {
            v += bv;
            v = 0.5f * v * (1.0f + erff(v * 0.70710678118654752f));
            outb[r * (long)cst + col] = f2bf(v);
          } else if constexpr (EPI == 2) {
            v += bv + bf2f(resid[r * (long)cst + col]);
            outf[r * (long)cst + col] = v;
          } else {
            v += bv + bf2f(resid[r * (long)cst + col]);
            outb[r * (long)cst + col] = f2bf(v);
          }
        }
      }
    }
  }
}

// ---------------- attn + LN (scores from scp partials, v from vb) ----------------
__global__ void __launch_bounds__(256) k_attn_ln(
    const unsigned short* __restrict__ xb, const unsigned short* __restrict__ vb,
    unsigned short* __restrict__ yb, const float* __restrict__ scp,
    const int* __restrict__ mask, const float* __restrict__ att_g,
    const float* __restrict__ att_b) {
  const int b = blockIdx.x * 4 + (threadIdx.x >> 6);
  const int lane = threadIdx.x & 63;
  const long base = (long)b * 5120 + lane * 16;

  float sc[5];
#pragma unroll
  for (int l = 0; l < 5; ++l) {
    const long r = (long)b * 5 + l;
    float s = 0.f;
#pragma unroll
    for (int k = 0; k < 16; ++k) s += scp[(long)k * NROWS + r];
    sc[l] = s * 0.03125f;
  }
  bool keep[5];
  float m = -1e30f;
#pragma unroll
  for (int l = 0; l < 5; ++l) {
    keep[l] = (mask[l] != 0);
    if (keep[l]) m = fmaxf(m, sc[l]);
  }
  float p[5], s = 0.f;
#pragma unroll
  for (int l = 0; l < 5; ++l) {
    p[l] = keep[l] ? __expf(sc[l] - m) : 0.f;
    s += p[l];
  }
  const float inv = 1.f / s;

  float gg[16], bb[16];
  {
    const float* gp = att_g + lane * 16;
    const float* bp = att_b + lane * 16;
#pragma unroll
    for (int q = 0; q < 4; ++q) {
      f32x4 gv = *(const f32x4*)(gp + q * 4);
      f32x4 bv = *(const f32x4*)(bp + q * 4);
#pragma unroll
      for (int c = 0; c < 4; ++c) { gg[q * 4 + c] = gv[c]; bb[q * 4 + c] = bv[c]; }
    }
  }

#pragma unroll
  for (int l = 0; l < 5; ++l) {
    const unsigned short* xp = xb + base + l * 1024;
    const unsigned short* vp = vb + base + l * 1024;
    float xr[16], vv[16];
    unpack8(*(const uint4*)xp, xr); unpack8(*(const uint4*)(xp + 8), xr + 8);
    unpack8(*(const uint4*)vp, vv); unpack8(*(const uint4*)(vp + 8), vv + 8);
    const float pl = p[l] * inv;
    float t[16], sm = 0.f, sq = 0.f;
#pragma unroll
    for (int c = 0; c < 16; ++c) {
      t[c] = pl * vv[c] + xr[c];
      sm += t[c];
      sq += t[c] * t[c];
    }
#pragma unroll
    for (int off = 32; off; off >>= 1) {
      sm += __shfl_xor(sm, off);
      sq += __shfl_xor(sq, off);
    }
    const float mu = sm * (1.f / 1024.f);
    const float var = sq * (1.f / 1024.f) - mu * mu;
    const float rs = rsqrtf(var + 1e-5f);
    unsigned short r[16];
#pragma unroll
    for (int c = 0; c < 16; ++c) r[c] = f2bf((t[c] - mu) * rs * gg[c] + bb[c]);
    uint4 o0, o1;
    o0.x = (unsigned)r[0] | ((unsigned)r[1] << 16);  o0.y = (unsigned)r[2] | ((unsigned)r[3] << 16);
    o0.z = (unsigned)r[4] | ((unsigned)r[5] << 16);  o0.w = (unsigned)r[6] | ((unsigned)r[7] << 16);
    o1.x = (unsigned)r[8] | ((unsigned)r[9] << 16);  o1.y = (unsigned)r[10] | ((unsigned)r[11] << 16);
    o1.z = (unsigned)r[12] | ((unsigned)r[13] << 16); o1.w = (unsigned)r[14] | ((unsigned)r[15] << 16);
    unsigned short* yp = yb + base + l * 1024;
    *(uint4*)yp = o0;
    *(uint4*)(yp + 8) = o1;
  }
}

// ---------------- final LN, bf16 z -> fp32 out ----------------
__global__ void __launch_bounds__(256) k_ln_final_bf(const unsigned short* __restrict__ zb,
                                                     float* __restrict__ out,
                                                     const float* __restrict__ g,
                                                     const float* __restrict__ bb) {
  const int lane = threadIdx.x & 63;
  const long row = (long)blockIdx.x * 4 + (threadIdx.x >> 6);
  const unsigned short* p = zb + row * DD + lane * 16;
  float t[16];
  unpack8(*(const uint4*)p, t);
  unpack8(*(const uint4*)(p + 8), t + 8);
  float sm = 0.f, sq = 0.f;
#pragma unroll
  for (int c = 0; c < 16; ++c) { sm += t[c]; sq += t[c] * t[c]; }
#pragma unroll
  for (int off = 32; off; off >>= 1) {
    sm += __shfl_xor(sm, off);
    sq += __shfl_xor(sq, off);
  }
  const float mu = sm * (1.f / 1024.f);
  const float var = sq * (1.f / 1024.f) - mu * mu;
  const float rs = rsqrtf(var + 1e-5f);
  float* op = out + row * DD + lane * 16;
  const float* gp = g + lane * 16;
  const float* bp = bb + lane * 16;
#pragma unroll
  for (int q = 0; q < 4; ++q) {
    f32x4 gv = *(const f32x4*)(gp + q * 4);
    f32x4 bv = *(const f32x4*)(bp + q * 4);
    f32x4 o;
#pragma unroll
    for (int c = 0; c < 4; ++c) o[c] = (t[q * 4 + c] - mu) * rs * gv[c] + bv[c];
    *(f32x4*)(op + q * 4) = o;
  }
}

// ---------------- final LN, fp32 z in-place (fallback, small ws) ----------------
__global__ void __launch_bounds__(256) k_ln_final(float* __restrict__ z,
                                                  const float* __restrict__ g,
                                                  const float* __restrict__ bb) {
  const int lane = threadIdx.x & 63;
  const long row = (long)blockIdx.x * 4 + (threadIdx.x >> 6);
  float* p = z + row * DD + lane * 16;
  f32x4 v[4];
  float sm = 0.f, sq = 0.f;
#pragma unroll
  for (int q = 0; q < 4; ++q) {
    v[q] = *(const f32x4*)(p + q * 4);
#pragma unroll
    for (int c = 0; c < 4; ++c) { sm += v[q][c]; sq += v[q][c] * v[q][c]; }
  }
#pragma unroll
  for (int off = 32; off; off >>= 1) {
    sm += __shfl_xor(sm, off);
    sq += __shfl_xor(sq, off);
  }
  const float mu = sm * (1.f / 1024.f);
  const float var = sq * (1.f / 1024.f) - mu * mu;
  const float rs = rsqrtf(var + 1e-5f);
  const float* gp = g + lane * 16;
  const float* bp = bb + lane * 16;
#pragma unroll
  for (int q = 0; q < 4; ++q) {
    f32x4 gv = *(const f32x4*)(gp + q * 4);
    f32x4 bv = *(const f32x4*)(bp + q * 4);
#pragma unroll
    for (int c = 0; c < 4; ++c) v[q][c] = (v[q][c] - mu) * rs * gv[c] + bv[c];
    *(f32x4*)(p + q * 4) = v[q];
  }
}

extern "C" void kernel_launch(void* const* d_in, const int* in_sizes, int n_in,
                              void* d_out, int out_size, void* d_ws, size_t ws_size,
                              hipStream_t stream) {
  const float* x     = (const float*)d_in[0];
  const int*   mask  = (const int*)d_in[1];
  const float* Wq    = (const float*)d_in[2];
  const float* Wk    = (const float*)d_in[3];
  const float* Wv    = (const float*)d_in[4];
  const float* W1    = (const float*)d_in[5];
  const float* b1    = (const float*)d_in[6];
  const float* W2    = (const float*)d_in[7];
  const float* b2    = (const float*)d_in[8];
  const float* att_g = (const float*)d_in[9];
  const float* att_b = (const float*)d_in[10];
  const float* ff_g  = (const float*)d_in[11];
  const float* ff_b  = (const float*)d_in[12];

  const long NE = NROWS * DD;
  unsigned short* xb   = (unsigned short*)d_ws;      // bf16 x, becomes y in place
  unsigned short* hb   = xb + NE;                    // GELU output
  unsigned short* Bcat = hb + NE;                    // [Gt ; Wv]  (2048 x 1024)
  unsigned short* W1b  = Bcat + 2L * DD * DD;
  unsigned short* W2b  = W1b + (long)DD * DD;
  float*          scp  = (float*)(W2b + (long)DD * DD);   // [16][M] dot partials
  unsigned short* zb   = (unsigned short*)(scp + 16 * NROWS);  // bf16 z (optional)

  const size_t need_zb = (size_t)(3L * NE + 4L * DD * DD) * 2 + 16 * NROWS * 4;
  const bool use_zb = ws_size >= need_zb;

  unsigned short* vb = (unsigned short*)d_out;       // [M][1024] bf16
  float* outf = (float*)d_out;

  k_cvt_bf16<<<2048, 256, 0, stream>>>(x, xb, NE);
  k_cvt_bf16<<<512, 256, 0, stream>>>(Wv, Bcat + (long)DD * DD, (long)DD * DD);
  k_cvt_bf16<<<512, 256, 0, stream>>>(W1, W1b, (long)DD * DD);
  k_cvt_bf16<<<512, 256, 0, stream>>>(W2, W2b, (long)DD * DD);
  k_gt<<<dim3(16, 64), dim3(16, 16), 0, stream>>>(Wq, Wk, Bcat);

  // xb @ Bcat^T : M=81920, N=2048 -> u-dot partials + v  (320*8 blocks)
  k_gemm256<0><<<2560, 512, 0, stream>>>(xb, Bcat, vb, nullptr, nullptr, nullptr, scp, 3, 1024);
  k_attn_ln<<<4096, 256, 0, stream>>>(xb, vb, xb, scp, mask, att_g, att_b);
  // h = GELU(y @ W1^T + b1) : N=1024 -> 320*4 blocks
  k_gemm256<1><<<1280, 512, 0, stream>>>(xb, W1b, hb, nullptr, b1, nullptr, nullptr, 2, 1024);
  if (use_zb) {
    // z = h @ W2^T + b2 + y -> bf16 zb, then LN -> fp32 d_out
    k_gemm256<3><<<1280, 512, 0, stream>>>(hb, W2b, zb, nullptr, b2, xb, nullptr, 2, 1024);
    k_ln_final_bf<<<20480, 256, 0, stream>>>(zb, outf, ff_g, ff_b);
  } else {
    k_gemm256<2><<<1280, 512, 0, stream>>>(hb, W2b, nullptr, outf, b2, xb, nullptr, 2, 1024);
    k_ln_final<<<20480, 256, 0, stream>>>(outf, ff_g, ff_b);
  }
}